// Round 8
// baseline (173.626 us; speedup 1.0000x reference)
//
#include <hip/hip_runtime.h>

#define N_NODES 8192
#define D_IN 512
#define D_OUT 64
#define LRELU_ALPHA 0.2f
#define KSPLIT 4
#define KSLICE (N_NODES / KSPLIT)   // 2048 cols per block
#define NCHUNK (KSLICE / 256)       // 8 chunks of 256 cols

typedef __attribute__((ext_vector_type(8))) short bf16x8;
typedef __attribute__((ext_vector_type(4))) float f32x4;

__device__ __forceinline__ unsigned short f2bf(float x) {
    unsigned u = __float_as_uint(x);
    u += 0x7fffu + ((u >> 16) & 1u);   // round-to-nearest-even
    return (unsigned short)(u >> 16);
}

// ---------------- Kernel 1: Wh = h @ W; epilogue writes WhTp(bf16, frag-order), Wh1, Wh2 ----------------
// WhTp layout: per feature n, per 64-col block: shorts [(m>>1)*32 + g*8 + (m&1)*4 + d]
// where col_in_block = g*4 + 16m + d  ->  each MFMA B fragment is one contiguous 16B.
__global__ __launch_bounds__(256) void k_gemm_wh(const float* __restrict__ h,
                                                 const float* __restrict__ W,
                                                 const float* __restrict__ a,
                                                 unsigned short* __restrict__ WhTp,
                                                 float* __restrict__ Wh1,
                                                 float* __restrict__ Wh2) {
    __shared__ float hs[32][68];
    __shared__ float Ws[64][64];
    const int tid = threadIdx.x;
    const int r0 = blockIdx.x * 32;
    const int tf = tid & 15;
    const int tr = tid >> 4;
    float acc[2][4] = {{0.f,0.f,0.f,0.f},{0.f,0.f,0.f,0.f}};

    for (int kc = 0; kc < D_IN; kc += 64) {
        {
            int rr = tid >> 4;
            int cc = (tid & 15) * 4;
            float4 v0 = *(const float4*)&h[(size_t)(r0 + rr) * D_IN + kc + cc];
            float4 v1 = *(const float4*)&h[(size_t)(r0 + rr + 16) * D_IN + kc + cc];
            *(float4*)&hs[rr][cc] = v0;
            *(float4*)&hs[rr + 16][cc] = v1;
        }
        #pragma unroll
        for (int p = 0; p < 4; ++p) {
            int kk = (tid >> 4) + p * 16;
            int cc = (tid & 15) * 4;
            *(float4*)&Ws[kk][cc] = *(const float4*)&W[(size_t)(kc + kk) * D_OUT + cc];
        }
        __syncthreads();
        #pragma unroll
        for (int k = 0; k < 64; k += 4) {
            float4 a0 = *(const float4*)&hs[tr*2][k];
            float4 a1 = *(const float4*)&hs[tr*2+1][k];
            float av0[4] = {a0.x, a0.y, a0.z, a0.w};
            float av1[4] = {a1.x, a1.y, a1.z, a1.w};
            #pragma unroll
            for (int kk = 0; kk < 4; ++kk) {
                float4 b = *(const float4*)&Ws[k+kk][tf*4];
                acc[0][0] += av0[kk]*b.x; acc[0][1] += av0[kk]*b.y;
                acc[0][2] += av0[kk]*b.z; acc[0][3] += av0[kk]*b.w;
                acc[1][0] += av1[kk]*b.x; acc[1][1] += av1[kk]*b.y;
                acc[1][2] += av1[kk]*b.z; acc[1][3] += av1[kk]*b.w;
            }
        }
        __syncthreads();
    }
    const int orow = r0 + tr*2;   // even

    // permuted WhTp write: cols (orow, orow+1) share (g,m), d even -> one 4B store
    {
        const int blk = orow >> 6;
        const int cw  = orow & 63;
        const int d   = cw & 3;
        const int gg  = (cw >> 2) & 3;
        const int m   = cw >> 4;
        const int soff = blk * 64 + (m >> 1) * 32 + gg * 8 + (m & 1) * 4 + d;
        #pragma unroll
        for (int k = 0; k < 4; ++k) {
            unsigned v = (unsigned)f2bf(acc[0][k]) | ((unsigned)f2bf(acc[1][k]) << 16);
            *(unsigned*)&WhTp[(size_t)(tf*4 + k) * N_NODES + soff] = v;
        }
    }

    float a1v[4], a2v[4];
    #pragma unroll
    for (int k = 0; k < 4; ++k) { a1v[k] = a[tf*4 + k]; a2v[k] = a[64 + tf*4 + k]; }
    float s1 = 0.f, t1 = 0.f, s2 = 0.f, t2 = 0.f;
    #pragma unroll
    for (int k = 0; k < 4; ++k) {
        s1 += acc[0][k] * a1v[k];
        t1 += acc[1][k] * a1v[k];
        s2 += acc[0][k] * a2v[k];
        t2 += acc[1][k] * a2v[k];
    }
    #pragma unroll
    for (int d = 1; d < 16; d <<= 1) {
        s1 += __shfl_xor(s1, d);
        t1 += __shfl_xor(t1, d);
        s2 += __shfl_xor(s2, d);
        t2 += __shfl_xor(t2, d);
    }
    if (tf == 0) {
        Wh1[orow] = s1; Wh1[orow + 1] = t1;
        Wh2[orow] = s2; Wh2[orow + 1] = t2;
    }
}

__device__ __forceinline__ float pgate(unsigned long long sd, int m, float w2v,
                                       float wh1v, float& lsum) {
    float e = wh1v + w2v;
    e = fmaxf(e, LRELU_ALPHA * e);                          // LeakyReLU
    float p = ((unsigned)(sd >> (4 * m)) & 1u) ? __expf(e) : 0.f;
    lsum += p;
    return p;
}

// ---------------- Kernel 2: FUSED mask-stream -> ballot bits (LDS) -> MFMA softmax/PV ----------------
// Grid = 512 row-blocks x KSPLIT(4) = 2048 blocks. Per chunk (16 rows x 256 cols):
//  A) coalesced mask tile load: 4 float4/thread, each wave = 1KB CONTIGUOUS of one row
//  B) 16 ballots -> lane0 writes 4 u64/row to parity-dbuf'd LDS (512B/chunk, 1 barrier)
//  C) each lane broadcast-reads its row's 4 u64; bit-gated p in A-fragment layout
//  D) 8 MFMA vs WhTp fragments (L2-hot).  Next chunk's mask loads issue before PCMF;
//     its ballots run after (HBM latency hides under compute). 256MB mask read once,
//     overlapped; k_maskbits kernel and bits round-trip eliminated.
__global__ __launch_bounds__(256, 4) void k_fused(const float* __restrict__ mask,
                                                  const unsigned short* __restrict__ WhTp,
                                                  const float* __restrict__ Wh1,
                                                  const float* __restrict__ Wh2,
                                                  float* __restrict__ pacc,
                                                  float* __restrict__ plsum) {
    __shared__ unsigned long long bitbuf[2][16][4];
    __shared__ float accbuf[4][16][68];
    __shared__ float lsumbuf[4][16];

    const int tid  = threadIdx.x;
    const int wave = tid >> 6;
    const int lane = tid & 63;
    const int i16 = lane & 15;
    const int g   = lane >> 4;
    const int rowblk = blockIdx.x >> 2;
    const int kslice = blockIdx.x & 3;
    const int R   = rowblk * 16;

    const float wh1v = Wh1[R + i16];
    // coalesced mask base: this thread reads rows (wave + 4*it), cols (lane*4..lane*4+3)
    const float* mbase = mask + (size_t)(R + wave) * N_NODES + kslice * KSLICE + lane * 4;
    const float* wh2s = Wh2 + kslice * KSLICE + wave * 64 + g * 4;
    const unsigned short* bbase = WhTp + (size_t)i16 * N_NODES
                                + (size_t)(kslice * (KSLICE / 64) + wave) * 64 + g * 8;
    const int sh = wave * 16 + g;

    f32x4 acc0 = {0.f,0.f,0.f,0.f}, acc1 = {0.f,0.f,0.f,0.f};
    f32x4 acc2 = {0.f,0.f,0.f,0.f}, acc3 = {0.f,0.f,0.f,0.f};
    float lsum = 0.f;

#define MLOAD(cc, M0,M1,M2,M3)                                        \
    {                                                                 \
        const float* mp_ = mbase + (cc) * 256;                        \
        M0 = *(const float4*)(mp_);                                   \
        M1 = *(const float4*)(mp_ + 4 * N_NODES);                     \
        M2 = *(const float4*)(mp_ + 8 * N_NODES);                     \
        M3 = *(const float4*)(mp_ + 12 * N_NODES);                    \
    }

#define BALLOT_STORE(par, M0,M1,M2,M3)                                \
    {                                                                 \
        unsigned long long b0, b1, b2, b3;                            \
        b0 = __ballot(M0.x > 0.f); b1 = __ballot(M0.y > 0.f);         \
        b2 = __ballot(M0.z > 0.f); b3 = __ballot(M0.w > 0.f);         \
        if (lane == 0) {                                              \
            ulonglong2 t; t.x = b0; t.y = b1;                         \
            *(ulonglong2*)&bitbuf[par][wave][0] = t;                  \
            t.x = b2; t.y = b3;                                       \
            *(ulonglong2*)&bitbuf[par][wave][2] = t;                  \
        }                                                             \
        b0 = __ballot(M1.x > 0.f); b1 = __ballot(M1.y > 0.f);         \
        b2 = __ballot(M1.z > 0.f); b3 = __ballot(M1.w > 0.f);         \
        if (lane == 0) {                                              \
            ulonglong2 t; t.x = b0; t.y = b1;                         \
            *(ulonglong2*)&bitbuf[par][4 + wave][0] = t;              \
            t.x = b2; t.y = b3;                                       \
            *(ulonglong2*)&bitbuf[par][4 + wave][2] = t;              \
        }                                                             \
        b0 = __ballot(M2.x > 0.f); b1 = __ballot(M2.y > 0.f);         \
        b2 = __ballot(M2.z > 0.f); b3 = __ballot(M2.w > 0.f);         \
        if (lane == 0) {                                              \
            ulonglong2 t; t.x = b0; t.y = b1;                         \
            *(ulonglong2*)&bitbuf[par][8 + wave][0] = t;              \
            t.x = b2; t.y = b3;                                       \
            *(ulonglong2*)&bitbuf[par][8 + wave][2] = t;              \
        }                                                             \
        b0 = __ballot(M3.x > 0.f); b1 = __ballot(M3.y > 0.f);         \
        b2 = __ballot(M3.z > 0.f); b3 = __ballot(M3.w > 0.f);         \
        if (lane == 0) {                                              \
            ulonglong2 t; t.x = b0; t.y = b1;                         \
            *(ulonglong2*)&bitbuf[par][12 + wave][0] = t;             \
            t.x = b2; t.y = b3;                                       \
            *(ulonglong2*)&bitbuf[par][12 + wave][2] = t;             \
        }                                                             \
    }

#define PCMF(cc, par)                                                             \
    {                                                                             \
        const ulonglong2 U01 = *(const ulonglong2*)&bitbuf[par][i16][0];          \
        const ulonglong2 U23 = *(const ulonglong2*)&bitbuf[par][i16][2];          \
        const float* wp_ = wh2s + (cc) * 256;                                     \
        const float4 W0 = *(const float4*)wp_;                                    \
        const float4 W1 = *(const float4*)(wp_ + 16);                             \
        const float4 W2 = *(const float4*)(wp_ + 32);                             \
        const float4 W3 = *(const float4*)(wp_ + 48);                             \
        const unsigned short* bb_ = bbase + (cc) * 256;                           \
        const bf16x8 B00 = *(const bf16x8*)(bb_);                                 \
        const bf16x8 B10 = *(const bf16x8*)(bb_ + 32);                            \
        const bf16x8 B01 = *(const bf16x8*)(bb_ + 16 * N_NODES);                  \
        const bf16x8 B11 = *(const bf16x8*)(bb_ + 16 * N_NODES + 32);             \
        const bf16x8 B02 = *(const bf16x8*)(bb_ + 32 * N_NODES);                  \
        const bf16x8 B12 = *(const bf16x8*)(bb_ + 32 * N_NODES + 32);             \
        const bf16x8 B03 = *(const bf16x8*)(bb_ + 48 * N_NODES);                  \
        const bf16x8 B13 = *(const bf16x8*)(bb_ + 48 * N_NODES + 32);             \
        const unsigned long long s0 = U01.x >> sh;                                \
        const unsigned long long s1 = U01.y >> sh;                                \
        const unsigned long long s2 = U23.x >> sh;                                \
        const unsigned long long s3 = U23.y >> sh;                                \
        bf16x8 af0, af1;                                                          \
        af0[0]=(short)f2bf(pgate(s0,0,W0.x,wh1v,lsum));                           \
        af0[1]=(short)f2bf(pgate(s1,0,W0.y,wh1v,lsum));                           \
        af0[2]=(short)f2bf(pgate(s2,0,W0.z,wh1v,lsum));                           \
        af0[3]=(short)f2bf(pgate(s3,0,W0.w,wh1v,lsum));                           \
        af0[4]=(short)f2bf(pgate(s0,1,W1.x,wh1v,lsum));                           \
        af0[5]=(short)f2bf(pgate(s1,1,W1.y,wh1v,lsum));                           \
        af0[6]=(short)f2bf(pgate(s2,1,W1.z,wh1v,lsum));                           \
        af0[7]=(short)f2bf(pgate(s3,1,W1.w,wh1v,lsum));                           \
        af1[0]=(short)f2bf(pgate(s0,2,W2.x,wh1v,lsum));                           \
        af1[1]=(short)f2bf(pgate(s1,2,W2.y,wh1v,lsum));                           \
        af1[2]=(short)f2bf(pgate(s2,2,W2.z,wh1v,lsum));                           \
        af1[3]=(short)f2bf(pgate(s3,2,W2.w,wh1v,lsum));                           \
        af1[4]=(short)f2bf(pgate(s0,3,W3.x,wh1v,lsum));                           \
        af1[5]=(short)f2bf(pgate(s1,3,W3.y,wh1v,lsum));                           \
        af1[6]=(short)f2bf(pgate(s2,3,W3.z,wh1v,lsum));                           \
        af1[7]=(short)f2bf(pgate(s3,3,W3.w,wh1v,lsum));                           \
        acc0 = __builtin_amdgcn_mfma_f32_16x16x32_bf16(af0, B00, acc0, 0, 0, 0);  \
        acc1 = __builtin_amdgcn_mfma_f32_16x16x32_bf16(af0, B01, acc1, 0, 0, 0);  \
        acc2 = __builtin_amdgcn_mfma_f32_16x16x32_bf16(af0, B02, acc2, 0, 0, 0);  \
        acc3 = __builtin_amdgcn_mfma_f32_16x16x32_bf16(af0, B03, acc3, 0, 0, 0);  \
        acc0 = __builtin_amdgcn_mfma_f32_16x16x32_bf16(af1, B10, acc0, 0, 0, 0);  \
        acc1 = __builtin_amdgcn_mfma_f32_16x16x32_bf16(af1, B11, acc1, 0, 0, 0);  \
        acc2 = __builtin_amdgcn_mfma_f32_16x16x32_bf16(af1, B12, acc2, 0, 0, 0);  \
        acc3 = __builtin_amdgcn_mfma_f32_16x16x32_bf16(af1, B13, acc3, 0, 0, 0);  \
    }

    // prologue: chunk 0 mask -> bits(par 0)
    float4 m0, m1, m2, m3;
    MLOAD(0, m0, m1, m2, m3);
    BALLOT_STORE(0, m0, m1, m2, m3);
    __syncthreads();

    #pragma unroll
    for (int c = 0; c < NCHUNK; ++c) {
        const int par = c & 1;
        if (c + 1 < NCHUNK) {
            MLOAD(c + 1, m0, m1, m2, m3);   // issue next-chunk mask loads early
        }
        PCMF(c, par);                        // compute hides the HBM latency
        if (c + 1 < NCHUNK) {
            BALLOT_STORE(par ^ 1, m0, m1, m2, m3);
        }
        __syncthreads();                     // bits[par^1] ready; reads of [par] done
    }

#undef MLOAD
#undef BALLOT_STORE
#undef PCMF

    // sum lsum across the 4 g-subgroups holding the same row
    lsum += __shfl_xor(lsum, 16);
    lsum += __shfl_xor(lsum, 32);
    if (lane < 16) lsumbuf[wave][lane] = lsum;

    // D layout (m89): row = g*4 + r, col = i16
    #pragma unroll
    for (int r = 0; r < 4; ++r) {
        accbuf[wave][g*4 + r][ 0 + i16] = acc0[r];
        accbuf[wave][g*4 + r][16 + i16] = acc1[r];
        accbuf[wave][g*4 + r][32 + i16] = acc2[r];
        accbuf[wave][g*4 + r][48 + i16] = acc3[r];
    }
    __syncthreads();

    const int tr  = tid >> 4;
    const int tf4 = (tid & 15) * 4;
    float4 s0 = *(const float4*)&accbuf[0][tr][tf4];
    float4 s1 = *(const float4*)&accbuf[1][tr][tf4];
    float4 s2 = *(const float4*)&accbuf[2][tr][tf4];
    float4 s3 = *(const float4*)&accbuf[3][tr][tf4];
    float4 o;
    o.x = s0.x + s1.x + s2.x + s3.x;
    o.y = s0.y + s1.y + s2.y + s3.y;
    o.z = s0.z + s1.z + s2.z + s3.z;
    o.w = s0.w + s1.w + s2.w + s3.w;
    *(float4*)&pacc[((size_t)kslice * N_NODES + R + tr) * D_OUT + tf4] = o;
    if (tid < 16) {
        plsum[(size_t)kslice * N_NODES + R + tid] =
            lsumbuf[0][tid] + lsumbuf[1][tid] +
            lsumbuf[2][tid] + lsumbuf[3][tid];
    }
}

// ---------------- Kernel 3: sum KSPLIT partials, normalize, ELU ----------------
__global__ __launch_bounds__(256) void k_finish(const float* __restrict__ pacc,
                                                const float* __restrict__ plsum,
                                                float* __restrict__ out) {
    const int idx = blockIdx.x * 256 + threadIdx.x;
    const int row = idx >> 4;
    const int tf4 = (idx & 15) * 4;
    float4 s = {0.f, 0.f, 0.f, 0.f};
    float L = 0.f;
    #pragma unroll
    for (int k = 0; k < KSPLIT; ++k) {
        float4 v = *(const float4*)&pacc[((size_t)k * N_NODES + row) * D_OUT + tf4];
        s.x += v.x; s.y += v.y; s.z += v.z; s.w += v.w;
        L += plsum[(size_t)k * N_NODES + row];
    }
    const float inv = (L > 0.f) ? 1.f / L : 0.f;
    float4 o;
    o.x = s.x * inv; o.y = s.y * inv; o.z = s.z * inv; o.w = s.w * inv;
    o.x = (o.x > 0.f) ? o.x : (__expf(o.x) - 1.f);
    o.y = (o.y > 0.f) ? o.y : (__expf(o.y) - 1.f);
    o.z = (o.z > 0.f) ? o.z : (__expf(o.z) - 1.f);
    o.w = (o.w > 0.f) ? o.w : (__expf(o.w) - 1.f);
    *(float4*)&out[(size_t)row * D_OUT + tf4] = o;
}

extern "C" void kernel_launch(void* const* d_in, const int* in_sizes, int n_in,
                              void* d_out, int out_size, void* d_ws, size_t ws_size,
                              hipStream_t stream) {
    const float* h    = (const float*)d_in[0];
    const float* mask = (const float*)d_in[1];
    // d_in[2] = lamda: unused (dischange==0 makes the mask-update a no-op)
    const float* W    = (const float*)d_in[3];
    const float* a    = (const float*)d_in[4];
    float* out = (float*)d_out;

    // ws: WhTp bf16 [64][8192] (1MB) | Wh1 (32KB) | Wh2 (32KB) | pacc (8MB) | plsum (128KB)
    unsigned short* WhTp = (unsigned short*)d_ws;
    float* Wh1 = (float*)((char*)d_ws + (size_t)D_OUT * N_NODES * sizeof(unsigned short));
    float* Wh2 = Wh1 + N_NODES;
    float* pacc = Wh2 + N_NODES;
    float* plsum = pacc + (size_t)KSPLIT * N_NODES * D_OUT;

    k_gemm_wh<<<N_NODES / 32, 256, 0, stream>>>(h, W, a, WhTp, Wh1, Wh2);
    k_fused<<<(N_NODES / 16) * KSPLIT, 256, 0, stream>>>(mask, WhTp, Wh1, Wh2, pacc, plsum);
    k_finish<<<(N_NODES * D_OUT / 4) / 256, 256, 0, stream>>>(pacc, plsum, out);
}

// Round 9
// 119.051 us; speedup vs baseline: 1.4584x; 1.4584x over previous
//
#include <hip/hip_runtime.h>

#define N_NODES 8192
#define D_IN 512
#define D_OUT 64
#define LRELU_ALPHA 0.2f
#define KSPLIT 4
#define KSLICE (N_NODES / KSPLIT)   // 2048 cols per block
#define NCHUNK (KSLICE / 256)       // 8 chunks of 256 cols

typedef __attribute__((ext_vector_type(8))) short bf16x8;
typedef __attribute__((ext_vector_type(4))) float f32x4;

__device__ __forceinline__ unsigned short f2bf(float x) {
    unsigned u = __float_as_uint(x);
    u += 0x7fffu + ((u >> 16) & 1u);   // round-to-nearest-even
    return (unsigned short)(u >> 16);
}

__device__ __forceinline__ float pgate(float mk, float w2v, float wh1v, float& lsum) {
    float e = wh1v + w2v;
    e = fmaxf(e, LRELU_ALPHA * e);   // LeakyReLU (monotone)
    float p = mk * __expf(e);        // mask is exactly 0.0/1.0; |e|<=~24 f32-safe
    lsum += p;
    return p;
}

// ---------------- Kernel 1: Wh = h @ W; epilogue writes WhTp(bf16, frag-order), Wh1, Wh2 ----------------
// WhTp layout: per feature n, per 64-col block: shorts [(m>>1)*32 + g*8 + (m&1)*4 + d]
// where col_in_block = g*4 + 16m + d  ->  each MFMA B fragment is one contiguous 16B.
__global__ __launch_bounds__(256) void k_gemm_wh(const float* __restrict__ h,
                                                 const float* __restrict__ W,
                                                 const float* __restrict__ a,
                                                 unsigned short* __restrict__ WhTp,
                                                 float* __restrict__ Wh1,
                                                 float* __restrict__ Wh2) {
    __shared__ float hs[32][68];
    __shared__ float Ws[64][64];
    const int tid = threadIdx.x;
    const int r0 = blockIdx.x * 32;
    const int tf = tid & 15;
    const int tr = tid >> 4;
    float acc[2][4] = {{0.f,0.f,0.f,0.f},{0.f,0.f,0.f,0.f}};

    for (int kc = 0; kc < D_IN; kc += 64) {
        {
            int rr = tid >> 4;
            int cc = (tid & 15) * 4;
            float4 v0 = *(const float4*)&h[(size_t)(r0 + rr) * D_IN + kc + cc];
            float4 v1 = *(const float4*)&h[(size_t)(r0 + rr + 16) * D_IN + kc + cc];
            *(float4*)&hs[rr][cc] = v0;
            *(float4*)&hs[rr + 16][cc] = v1;
        }
        #pragma unroll
        for (int p = 0; p < 4; ++p) {
            int kk = (tid >> 4) + p * 16;
            int cc = (tid & 15) * 4;
            *(float4*)&Ws[kk][cc] = *(const float4*)&W[(size_t)(kc + kk) * D_OUT + cc];
        }
        __syncthreads();
        #pragma unroll
        for (int k = 0; k < 64; k += 4) {
            float4 a0 = *(const float4*)&hs[tr*2][k];
            float4 a1 = *(const float4*)&hs[tr*2+1][k];
            float av0[4] = {a0.x, a0.y, a0.z, a0.w};
            float av1[4] = {a1.x, a1.y, a1.z, a1.w};
            #pragma unroll
            for (int kk = 0; kk < 4; ++kk) {
                float4 b = *(const float4*)&Ws[k+kk][tf*4];
                acc[0][0] += av0[kk]*b.x; acc[0][1] += av0[kk]*b.y;
                acc[0][2] += av0[kk]*b.z; acc[0][3] += av0[kk]*b.w;
                acc[1][0] += av1[kk]*b.x; acc[1][1] += av1[kk]*b.y;
                acc[1][2] += av1[kk]*b.z; acc[1][3] += av1[kk]*b.w;
            }
        }
        __syncthreads();
    }
    const int orow = r0 + tr*2;   // even

    // permuted WhTp write: cols (orow, orow+1) share (g,m), d even -> one 4B store
    {
        const int blk = orow >> 6;
        const int cw  = orow & 63;
        const int d   = cw & 3;
        const int gg  = (cw >> 2) & 3;
        const int m   = cw >> 4;
        const int soff = blk * 64 + (m >> 1) * 32 + gg * 8 + (m & 1) * 4 + d;
        #pragma unroll
        for (int k = 0; k < 4; ++k) {
            unsigned v = (unsigned)f2bf(acc[0][k]) | ((unsigned)f2bf(acc[1][k]) << 16);
            *(unsigned*)&WhTp[(size_t)(tf*4 + k) * N_NODES + soff] = v;
        }
    }

    float a1v[4], a2v[4];
    #pragma unroll
    for (int k = 0; k < 4; ++k) { a1v[k] = a[tf*4 + k]; a2v[k] = a[64 + tf*4 + k]; }
    float s1 = 0.f, t1 = 0.f, s2 = 0.f, t2 = 0.f;
    #pragma unroll
    for (int k = 0; k < 4; ++k) {
        s1 += acc[0][k] * a1v[k];
        t1 += acc[1][k] * a1v[k];
        s2 += acc[0][k] * a2v[k];
        t2 += acc[1][k] * a2v[k];
    }
    #pragma unroll
    for (int d = 1; d < 16; d <<= 1) {
        s1 += __shfl_xor(s1, d);
        t1 += __shfl_xor(t1, d);
        s2 += __shfl_xor(s2, d);
        t2 += __shfl_xor(t2, d);
    }
    if (tf == 0) {
        Wh1[orow] = s1; Wh1[orow + 1] = t1;
        Wh2[orow] = s2; Wh2[orow + 1] = t2;
    }
}

// ---------------- Kernel 2: DMA-pipelined fused mask-stream + MFMA softmax/PV ----------------
// Grid = 512 row-blocks x KSPLIT(4). Per 16x256 chunk (16KB):
//  - each WAVE global_load_lds's exactly the granules it will read (region [m][wave][lane]):
//    wave-local -> NO barriers in the main loop; sync = per-wave counted vmcnt (3 bufs, depth 2).
//  - reader ds_read_b128 at lane*16: conflict-free; DMA dest is linear (m104 constraint ok).
//  - p = mask * exp(lrelu(wh1+wh2)) straight from LDS f32 (no ballot/bits).
//  - B fragments: 8x16B L2-hot VGPR loads issued at iter top (WhTp is 1MB, L2-resident).
__global__ __launch_bounds__(256, 2) void k_fused(const float* __restrict__ mask,
                                                  const unsigned short* __restrict__ WhTp,
                                                  const float* __restrict__ Wh1,
                                                  const float* __restrict__ Wh2,
                                                  float* __restrict__ pacc,
                                                  float* __restrict__ plsum) {
    __shared__ float wh2lds[KSLICE];          // 8 KB
    __shared__ float mbuf[3][4][4][256];      // 3 x 16 KB mask chunk buffers [buf][m][wave][lane*4]
    __shared__ float accbuf[4][16][68];       // 17.4 KB
    __shared__ float lsumbuf[4][16];

    const int tid  = threadIdx.x;
    const int wave = tid >> 6;
    const int lane = tid & 63;
    const int i16 = lane & 15;
    const int g   = lane >> 4;
    const int rowblk = blockIdx.x >> 2;
    const int kslice = blockIdx.x & 3;
    const int R   = rowblk * 16;
    const int kbase = kslice * KSLICE;

    // stage Wh2 k-slice (8 KB) once
    *(float4*)&wh2lds[tid * 4]        = *(const float4*)&Wh2[kbase + tid * 4];
    *(float4*)&wh2lds[1024 + tid * 4] = *(const float4*)&Wh2[kbase + 1024 + tid * 4];
    const float wh1v = Wh1[R + i16];
    asm volatile("" :: "v"(wh1v));   // materialize before loop (avoid vmcnt(0) inside PCMF(0))
    __syncthreads();

    const unsigned short* bbase = WhTp + (size_t)i16 * N_NODES
                                + (size_t)(kslice * (KSLICE / 64) + wave) * 64 + g * 8;

    f32x4 acc0 = {0.f,0.f,0.f,0.f}, acc1 = {0.f,0.f,0.f,0.f};
    f32x4 acc2 = {0.f,0.f,0.f,0.f}, acc3 = {0.f,0.f,0.f,0.f};
    float lsum = 0.f;

    // wave-local DMA: wave stages granules (m=0..3) it will itself read.
    // lane L writes/reads element (row = L&15, col = c*256 + wave*64 + m*16 + (L>>4)*4).
#define DMAISSUE(cc, bi)                                                          \
    {                                                                             \
        const float* gsrc_ = mask + (size_t)(R + i16) * N_NODES                   \
                           + kbase + (cc) * 256 + wave * 64 + g * 4;              \
        __builtin_amdgcn_global_load_lds(gsrc_,      &mbuf[bi][0][wave][0], 16, 0, 0); \
        __builtin_amdgcn_global_load_lds(gsrc_ + 16, &mbuf[bi][1][wave][0], 16, 0, 0); \
        __builtin_amdgcn_global_load_lds(gsrc_ + 32, &mbuf[bi][2][wave][0], 16, 0, 0); \
        __builtin_amdgcn_global_load_lds(gsrc_ + 48, &mbuf[bi][3][wave][0], 16, 0, 0); \
    }

#define PCMF(cc, bi)                                                              \
    {                                                                             \
        const float4 M0 = *(const float4*)&mbuf[bi][0][wave][lane * 4];           \
        const float4 M1 = *(const float4*)&mbuf[bi][1][wave][lane * 4];           \
        const float4 M2 = *(const float4*)&mbuf[bi][2][wave][lane * 4];           \
        const float4 M3 = *(const float4*)&mbuf[bi][3][wave][lane * 4];           \
        const float4 W0 = *(const float4*)&wh2lds[(cc) * 256 + wave * 64 + g * 4];       \
        const float4 W1 = *(const float4*)&wh2lds[(cc) * 256 + wave * 64 + 16 + g * 4];  \
        const float4 W2 = *(const float4*)&wh2lds[(cc) * 256 + wave * 64 + 32 + g * 4];  \
        const float4 W3 = *(const float4*)&wh2lds[(cc) * 256 + wave * 64 + 48 + g * 4];  \
        bf16x8 af0, af1;                                                          \
        af0[0]=(short)f2bf(pgate(M0.x,W0.x,wh1v,lsum));                           \
        af0[1]=(short)f2bf(pgate(M0.y,W0.y,wh1v,lsum));                           \
        af0[2]=(short)f2bf(pgate(M0.z,W0.z,wh1v,lsum));                           \
        af0[3]=(short)f2bf(pgate(M0.w,W0.w,wh1v,lsum));                           \
        af0[4]=(short)f2bf(pgate(M1.x,W1.x,wh1v,lsum));                           \
        af0[5]=(short)f2bf(pgate(M1.y,W1.y,wh1v,lsum));                           \
        af0[6]=(short)f2bf(pgate(M1.z,W1.z,wh1v,lsum));                           \
        af0[7]=(short)f2bf(pgate(M1.w,W1.w,wh1v,lsum));                           \
        af1[0]=(short)f2bf(pgate(M2.x,W2.x,wh1v,lsum));                           \
        af1[1]=(short)f2bf(pgate(M2.y,W2.y,wh1v,lsum));                           \
        af1[2]=(short)f2bf(pgate(M2.z,W2.z,wh1v,lsum));                           \
        af1[3]=(short)f2bf(pgate(M2.w,W2.w,wh1v,lsum));                           \
        af1[4]=(short)f2bf(pgate(M3.x,W3.x,wh1v,lsum));                           \
        af1[5]=(short)f2bf(pgate(M3.y,W3.y,wh1v,lsum));                           \
        af1[6]=(short)f2bf(pgate(M3.z,W3.z,wh1v,lsum));                           \
        af1[7]=(short)f2bf(pgate(M3.w,W3.w,wh1v,lsum));                           \
        acc0 = __builtin_amdgcn_mfma_f32_16x16x32_bf16(af0, B00, acc0, 0, 0, 0);  \
        acc1 = __builtin_amdgcn_mfma_f32_16x16x32_bf16(af0, B01, acc1, 0, 0, 0);  \
        acc2 = __builtin_amdgcn_mfma_f32_16x16x32_bf16(af0, B02, acc2, 0, 0, 0);  \
        acc3 = __builtin_amdgcn_mfma_f32_16x16x32_bf16(af0, B03, acc3, 0, 0, 0);  \
        acc0 = __builtin_amdgcn_mfma_f32_16x16x32_bf16(af1, B10, acc0, 0, 0, 0);  \
        acc1 = __builtin_amdgcn_mfma_f32_16x16x32_bf16(af1, B11, acc1, 0, 0, 0);  \
        acc2 = __builtin_amdgcn_mfma_f32_16x16x32_bf16(af1, B12, acc2, 0, 0, 0);  \
        acc3 = __builtin_amdgcn_mfma_f32_16x16x32_bf16(af1, B13, acc3, 0, 0, 0);  \
    }

    // ITER: [B(c) loads] [DMA(c+2) issue] [vmcnt: DMA(c) done] [ds_read + VALU + MFMA]
    // Waits chosen conservatively LOW (safe direction): steady state leaves >= chunk c+2
    // in flight; compiler's own B-use wait may drain c+1 early (perf-only).
#define ITER(cc, bi, pfbi, VN, DOPF)                                              \
    {                                                                             \
        const unsigned short* bb_ = bbase + (cc) * 256;                           \
        const bf16x8 B00 = *(const bf16x8*)(bb_);                                 \
        const bf16x8 B10 = *(const bf16x8*)(bb_ + 32);                            \
        const bf16x8 B01 = *(const bf16x8*)(bb_ + 16 * N_NODES);                  \
        const bf16x8 B11 = *(const bf16x8*)(bb_ + 16 * N_NODES + 32);             \
        const bf16x8 B02 = *(const bf16x8*)(bb_ + 32 * N_NODES);                  \
        const bf16x8 B12 = *(const bf16x8*)(bb_ + 32 * N_NODES + 32);             \
        const bf16x8 B03 = *(const bf16x8*)(bb_ + 48 * N_NODES);                  \
        const bf16x8 B13 = *(const bf16x8*)(bb_ + 48 * N_NODES + 32);             \
        __builtin_amdgcn_sched_barrier(0);                                        \
        if (DOPF) DMAISSUE((cc) + 2, pfbi);                                       \
        __builtin_amdgcn_sched_barrier(0);                                        \
        asm volatile("s_waitcnt vmcnt(" VN ")" ::: "memory");                     \
        __builtin_amdgcn_sched_barrier(0);                                        \
        PCMF(cc, bi);                                                             \
    }

    // prologue: chunks 0,1 in flight
    DMAISSUE(0, 0);
    DMAISSUE(1, 1);

    ITER(0, 0, 2, "12", 1);
    ITER(1, 1, 0, "12", 1);
    ITER(2, 2, 1, "12", 1);
    ITER(3, 0, 2, "12", 1);
    ITER(4, 1, 0, "12", 1);
    ITER(5, 2, 1, "12", 1);
    ITER(6, 0, 0, "8",  0);
    ITER(7, 1, 0, "4",  0);

#undef DMAISSUE
#undef PCMF
#undef ITER

    // sum lsum across the 4 g-subgroups holding the same row
    lsum += __shfl_xor(lsum, 16);
    lsum += __shfl_xor(lsum, 32);
    if (lane < 16) lsumbuf[wave][lane] = lsum;

    // D layout (m89): row = g*4 + r, col = i16
    #pragma unroll
    for (int r = 0; r < 4; ++r) {
        accbuf[wave][g*4 + r][ 0 + i16] = acc0[r];
        accbuf[wave][g*4 + r][16 + i16] = acc1[r];
        accbuf[wave][g*4 + r][32 + i16] = acc2[r];
        accbuf[wave][g*4 + r][48 + i16] = acc3[r];
    }
    __syncthreads();

    const int tr  = tid >> 4;
    const int tf4 = (tid & 15) * 4;
    float4 s0 = *(const float4*)&accbuf[0][tr][tf4];
    float4 s1 = *(const float4*)&accbuf[1][tr][tf4];
    float4 s2 = *(const float4*)&accbuf[2][tr][tf4];
    float4 s3 = *(const float4*)&accbuf[3][tr][tf4];
    float4 o;
    o.x = s0.x + s1.x + s2.x + s3.x;
    o.y = s0.y + s1.y + s2.y + s3.y;
    o.z = s0.z + s1.z + s2.z + s3.z;
    o.w = s0.w + s1.w + s2.w + s3.w;
    *(float4*)&pacc[((size_t)kslice * N_NODES + R + tr) * D_OUT + tf4] = o;
    if (tid < 16) {
        plsum[(size_t)kslice * N_NODES + R + tid] =
            lsumbuf[0][tid] + lsumbuf[1][tid] +
            lsumbuf[2][tid] + lsumbuf[3][tid];
    }
}

// ---------------- Kernel 3: sum KSPLIT partials, normalize, ELU ----------------
__global__ __launch_bounds__(256) void k_finish(const float* __restrict__ pacc,
                                                const float* __restrict__ plsum,
                                                float* __restrict__ out) {
    const int idx = blockIdx.x * 256 + threadIdx.x;
    const int row = idx >> 4;
    const int tf4 = (idx & 15) * 4;
    float4 s = {0.f, 0.f, 0.f, 0.f};
    float L = 0.f;
    #pragma unroll
    for (int k = 0; k < KSPLIT; ++k) {
        float4 v = *(const float4*)&pacc[((size_t)k * N_NODES + row) * D_OUT + tf4];
        s.x += v.x; s.y += v.y; s.z += v.z; s.w += v.w;
        L += plsum[(size_t)k * N_NODES + row];
    }
    const float inv = (L > 0.f) ? 1.f / L : 0.f;
    float4 o;
    o.x = s.x * inv; o.y = s.y * inv; o.z = s.z * inv; o.w = s.w * inv;
    o.x = (o.x > 0.f) ? o.x : (__expf(o.x) - 1.f);
    o.y = (o.y > 0.f) ? o.y : (__expf(o.y) - 1.f);
    o.z = (o.z > 0.f) ? o.z : (__expf(o.z) - 1.f);
    o.w = (o.w > 0.f) ? o.w : (__expf(o.w) - 1.f);
    *(float4*)&out[(size_t)row * D_OUT + tf4] = o;
}

extern "C" void kernel_launch(void* const* d_in, const int* in_sizes, int n_in,
                              void* d_out, int out_size, void* d_ws, size_t ws_size,
                              hipStream_t stream) {
    const float* h    = (const float*)d_in[0];
    const float* mask = (const float*)d_in[1];
    // d_in[2] = lamda: unused (dischange==0 makes the mask-update a no-op)
    const float* W    = (const float*)d_in[3];
    const float* a    = (const float*)d_in[4];
    float* out = (float*)d_out;

    // ws: WhTp bf16 [64][8192] (1MB) | Wh1 (32KB) | Wh2 (32KB) | pacc (8MB) | plsum (128KB)
    unsigned short* WhTp = (unsigned short*)d_ws;
    float* Wh1 = (float*)((char*)d_ws + (size_t)D_OUT * N_NODES * sizeof(unsigned short));
    float* Wh2 = Wh1 + N_NODES;
    float* pacc = Wh2 + N_NODES;
    float* plsum = pacc + (size_t)KSPLIT * N_NODES * D_OUT;

    k_gemm_wh<<<N_NODES / 32, 256, 0, stream>>>(h, W, a, WhTp, Wh1, Wh2);
    k_fused<<<(N_NODES / 16) * KSPLIT, 256, 0, stream>>>(mask, WhTp, Wh1, Wh2, pacc, plsum);
    k_finish<<<(N_NODES * D_OUT / 4) / 256, 256, 0, stream>>>(pacc, plsum, out);
}